// Round 12
// baseline (232.464 us; speedup 1.0000x reference)
//
#include <hip/hip_runtime.h>
#include <hip/hip_bf16.h>

// 2-layer GCN + mean pool. N=100000, E=1600000, G=128. dims 3 -> 64 -> 128.
//   h1  = relu( (A_hat x) @ W1 + b1 )
//   out = (mean_g (A_hat h1)) @ W2 + b2
//
// R21 -> R22 (revert gather2 8-deep; deg counted in k_split):
//   * k_gather2 REVERTED to R20's 4-deep unroll (8-deep was 48.5 -> 54.8us:
//     occupancy 55 -> 48.5%. gather2 is queue-bound at ~48us floor —
//     insensitive to MLP depth (R21) and FETCH volume (R14). FROZEN.)
//   * deg counting moved INTO k_split (1 global atomicAdd per edge,
//     ~16-way mean contention over 400KB). k_deg shrunk to a pure
//     per-node pass: coalesced deg/x/batch reads -> xs/start writes.
//     Drops k_deg's 6.4MB edges2 re-read + LDS histogram (~-8us).
//   * gcur+deg contiguous -> single memset covers both.
//   k_sortl1 (inline mbase, R21) / k_out unchanged. 6 dispatches.

typedef __hip_bfloat16 bf16;
#define NGRAPH 128
#define NSLICE 8
#define TILE_S 4096
#define CAPLG  13      // per-bucket edges2 capacity = 8192
#define SCAP   8192    // k_sortl1 LDS stage capacity (mean 4096+256, 60 sigma)

__device__ __forceinline__ float b2f(bf16 v) { return __bfloat162float(v); }
__device__ __forceinline__ float fld(const void* p, long long i, int isbf) {
    return isbf ? b2f(((const bf16*)p)[i]) : ((const float*)p)[i];
}
__device__ __forceinline__ int ild(const void* p, long long i, int is64) {
    return is64 ? (int)((const long long*)p)[i] : ((const int*)p)[i];
}
// dtype probes: 2 cache lines each on LARGE buffers only (x: 600KB+, ei: 12MB+)
__device__ __forceinline__ int probe_is64(const void* ei) {
    int lane = threadIdx.x & 63;
    const int* w = (const int*)ei;
    unsigned long long bz = __ballot(w[2 * lane + 1] == 0);
    return (__popcll(bz) >= 56) ? 1 : 0;
}
__device__ __forceinline__ int probe_isbf(const void* x) {
    int lane = threadIdx.x & 63;
    const unsigned short* u = (const unsigned short*)x;
    int e0 = (u[2 * lane] >> 7) & 0xFF;
    int e1 = (u[2 * (lane + 64)] >> 7) & 0xFF;
    int good = __popcll(__ballot(e0 >= 90 && e0 <= 135))
             + __popcll(__ballot(e1 >= 90 && e1 <= 135));
    return (good >= 96) ? 1 : 0;
}

// ---- multisplit by dst bucket, self-counting, single ei read ------------
// edges2[b<<CAPLG ... ] = src | dloc<<24 for bucket b; gcur[b] ends = count.
// Also counts per-node degree via global atomics (deg zero-init by memset).
__global__ void k_split(const void* __restrict__ ei, unsigned* __restrict__ edges2,
                        int* __restrict__ gcur, int* __restrict__ deg,
                        float4* __restrict__ P4, int E, int NB) {
    // stripe-zero P (16384 float4s); safe: gather2 launches much later
    for (int k = blockIdx.x * 256 + threadIdx.x; k < NSLICE * NGRAPH * 16;
         k += gridDim.x * 256)
        P4[k] = make_float4(0.f, 0.f, 0.f, 0.f);
    __shared__ int hist[512], scan_[512], gbase[512], lcur[512];
    __shared__ int2 stage[TILE_S];
    int is64 = probe_is64(ei);
    long long base = (long long)blockIdx.x * TILE_S;
    int lim = (int)min((long long)TILE_S, (long long)E - base);
    for (int b = threadIdx.x; b < 512; b += 256) hist[b] = 0;
    __syncthreads();
    int dreg[16], sreg[16];
#pragma unroll
    for (int j = 0; j < 16; ++j) {
        int k = threadIdx.x + (j << 8);
        if (k < lim) {
            int d = ild(ei, (long long)E + base + k, is64);
            int s = ild(ei, base + k, is64);
            dreg[j] = d; sreg[j] = s;
            atomicAdd(&hist[d >> 8], 1);
            atomicAdd(&deg[d], 1);
        } else dreg[j] = -1;
    }
    __syncthreads();
    // parallel exclusive scan of hist (512 entries, 256 threads, Hillis-Steele)
    {
        int i0 = threadIdx.x, i1 = threadIdx.x + 256;
        scan_[i0] = hist[i0]; scan_[i1] = hist[i1];
        __syncthreads();
        for (int d = 1; d < 512; d <<= 1) {
            int t0 = (i0 >= d) ? scan_[i0 - d] : 0;
            int t1 = (i1 >= d) ? scan_[i1 - d] : 0;
            __syncthreads();
            scan_[i0] += t0; scan_[i1] += t1;
            __syncthreads();
        }
        int e0 = scan_[i0] - hist[i0];
        int e1 = scan_[i1] - hist[i1];
        __syncthreads();
        scan_[i0] = e0; scan_[i1] = e1;
        __syncthreads();
    }
    for (int b = threadIdx.x; b < NB; b += 256) {
        lcur[b] = scan_[b];
        gbase[b] = hist[b] ? atomicAdd(&gcur[b], hist[b]) : 0;
    }
    __syncthreads();
#pragma unroll
    for (int j = 0; j < 16; ++j) {
        if (dreg[j] >= 0) {
            int p = atomicAdd(&lcur[dreg[j] >> 8], 1);
            stage[p] = make_int2(dreg[j], sreg[j]);
        }
    }
    __syncthreads();
    for (int t = threadIdx.x; t < lim; t += 256) {
        int2 r = stage[t];
        int b = r.x >> 8;
        edges2[((size_t)b << CAPLG) + gbase[b] + (t - scan_[b])] =
            (unsigned)r.y | ((unsigned)(r.x & 255) << 24);
    }
}

// ---- per-node pass: xs = dinv*x, start (deg already counted) ------------
__global__ void k_deg(const void* __restrict__ batch, const void* __restrict__ x,
                      const void* __restrict__ ei, const int* __restrict__ deg,
                      float4* __restrict__ xs, int* __restrict__ start, int N) {
    int is64 = probe_is64(ei);
    int isbf = probe_isbf(x);
    int node = blockIdx.x * 256 + threadIdx.x;
    if (node < N) {
        int dg = deg[node];
        float di = rsqrtf((float)(dg + 1));
        xs[node] = make_float4(di * fld(x, 3LL * node, isbf),
                               di * fld(x, 3LL * node + 1, isbf),
                               di * fld(x, 3LL * node + 2, isbf), 0.0f);
        int g = ild(batch, node, is64);
        int gp = (node == 0) ? -1 : ild(batch, node - 1, is64);
        for (int q = gp + 1; q <= g; ++q) start[q] = node;
        if (node == N - 1)
            for (int q = g + 1; q <= NGRAPH; ++q) start[q] = N;
    }
}

// ---- fused: counting-sort meta build + layer-1 GEMM --------------------
// meta = src | g<<17 | min(deg,255)<<24; slot 0 of each row = self record.
// mbase computed inline: bktoff[b] = sum_{j<b} gcur[j] + node0 (nloc==256
// for all j<b). Aggregation reads LDS stage; hs1 written here.
__global__ void k_sortl1(const unsigned* __restrict__ edges2, const void* __restrict__ batch,
                         const void* __restrict__ x, const void* __restrict__ ei,
                         const int* __restrict__ gcur,
                         const int* __restrict__ deg, const float4* __restrict__ xs,
                         const void* __restrict__ W1, const void* __restrict__ b1,
                         unsigned* __restrict__ meta, bf16* __restrict__ hs1, int N) {
    __shared__ int loff[257], lcur[256], sc[256];
    __shared__ unsigned gdeg[256];
    __shared__ unsigned stage[SCAP];
    __shared__ float w[256];        // [0..191]=W1 (3x64 row-major), [192..255]=b1
    __shared__ float ag[256][4];
    int b = blockIdx.x;
    int node0 = b << 8;
    int nloc = min(256, N - node0);
    int is64 = probe_is64(ei);
    int isbf = probe_isbf(x);
    int i = threadIdx.x;
    if (i < 192) w[i] = fld(W1, i, isbf);
    if (i < 64) w[192 + i] = fld(b1, i, isbf);
    size_t rbase = (size_t)b << CAPLG;
    int rcnt = gcur[b];
    // inline mbase: block-reduce sum of gcur[0..b-1]
    int partial = 0;
    for (int j = i; j < b; j += 256) partial += gcur[j];
    sc[i] = partial;
    __syncthreads();
    for (int d = 128; d > 0; d >>= 1) {
        if (i < d) sc[i] += sc[i + d];
        __syncthreads();
    }
    int mbase = sc[0] + node0;
    __syncthreads();
    // register-cache first 4096 records (record 0xFFFFFFFF impossible: src<2^17)
    unsigned rc[16];
    int ncache = min(rcnt, 4096);
#pragma unroll
    for (int j = 0; j < 16; ++j) {
        int t = i + (j << 8);
        rc[j] = (t < ncache) ? edges2[rbase + t] : 0xFFFFFFFFu;
    }
    int dg = (i < nloc) ? deg[node0 + i] : 0;
    // exclusive scan of (deg+1)
    int v = (i < nloc) ? dg + 1 : 0;
    sc[i] = v;
    __syncthreads();
    for (int d = 1; d < 256; d <<= 1) {
        int t = (i >= d) ? sc[i - d] : 0;
        __syncthreads();
        sc[i] += t;
        __syncthreads();
    }
    if (i < nloc) loff[i] = sc[i] - v;
    if (i == nloc - 1) loff[nloc] = sc[i];
    __syncthreads();
    if (i < nloc) {
        int node = node0 + i;
        int g = ild(batch, node, is64);
        unsigned gd = ((unsigned)g << 17) | ((unsigned)min(dg, 255) << 24);
        gdeg[i] = gd;
        lcur[i] = loff[i] + 1;                 // slot 0 = self record
        stage[loff[i]] = (unsigned)node | gd;
    }
    __syncthreads();
#pragma unroll
    for (int j = 0; j < 16; ++j) {
        if (rc[j] != 0xFFFFFFFFu) {
            int dl = (int)(rc[j] >> 24);
            int p = atomicAdd(&lcur[dl], 1);
            if (p < SCAP) stage[p] = (rc[j] & 0x1FFFFu) | gdeg[dl];
        }
    }
    for (int t = 4096 + i; t < rcnt; t += 256) {
        unsigned r = edges2[rbase + t];
        int dl = (int)(r >> 24);
        int p = atomicAdd(&lcur[dl], 1);
        if (p < SCAP) stage[p] = (r & 0x1FFFFu) | gdeg[dl];
    }
    __syncthreads();
    int total = loff[nloc];
    int totc = min(total, SCAP);
    for (int t = i; t < totc; t += 256) meta[mbase + t] = stage[t];
    // layer-1 aggregation from LDS stage + tiny GEMM
    if (i < nloc) {
        float ax = 0.f, ay = 0.f, az = 0.f;
        int p1 = min(loff[i + 1], SCAP);
        for (int p = loff[i]; p < p1; ++p) {
            float4 vv = xs[stage[p] & 0x1FFFFu];
            ax += vv.x; ay += vv.y; az += vv.z;
        }
        float di = rsqrtf((float)(dg + 1));
        ag[i][0] = di * ax; ag[i][1] = di * ay; ag[i][2] = di * az;
        ag[i][3] = di;
    }
    __syncthreads();
    for (int t = i; t < (nloc << 6); t += 256) {
        int ii = t >> 6, j = t & 63;
        float acc = ag[ii][0] * w[j] + ag[ii][1] * w[64 + j] + ag[ii][2] * w[128 + j]
                  + w[192 + j];
        hs1[(size_t)(node0 + ii) * 64 + j] = __float2bfloat16(ag[ii][3] * fmaxf(acc, 0.0f));
    }
}

// ---- layer 2 + pool: edge-balanced meta stream (register acc) -----------
// Wave = 8 groups x 8 lanes. Group q walks edges base+q, base+q+8, ... (a
// stride-8 subsequence of the dst-sorted stream -> g stays monotone). Each
// lane loads 16B (uint4 = 8 bf16) of the 128B hs1 row: one dwordx4
// instruction fetches 8 edges' rows (1KB). 4-deep unroll (R20-proven best:
// 8-deep regressed via occupancy). Register acc; R13 flush discipline.
__global__ void k_gather2(const uint4* __restrict__ hs1q, const unsigned* __restrict__ meta,
                          float* __restrict__ P, int Etot, int chunk) {
    int wid = (blockIdx.x * blockDim.x + threadIdx.x) >> 6;
    int lane = threadIdx.x & 63;
    int q = lane >> 3;          // group 0..7
    int l8 = lane & 7;          // lane in group -> features [8*l8, 8*l8+8)
    long long base = (long long)wid * chunk;
    if (base >= Etot) return;
    long long end = base + chunk;
    if (end > Etot) end = Etot;
    float acc[8] = {0.f, 0.f, 0.f, 0.f, 0.f, 0.f, 0.f, 0.f};
    int gcur = -1;
#define GFLUSH()                                                                \
    if (gcur >= 0) {                                                            \
        float* dp = P + (size_t)q * (NGRAPH * 64) + (size_t)gcur * 64 + (l8 << 3); \
        _Pragma("unroll")                                                       \
        for (int k = 0; k < 8; ++k) { atomicAdd(dp + k, acc[k]); acc[k] = 0.f; }\
    }
#define STEP(m, v)                                                              \
    {                                                                           \
        int g = (int)((m >> 17) & 0x7Fu);                                       \
        float w = rsqrtf((float)((m >> 24) & 0xFFu) + 1.0f);                    \
        if (g != gcur) { GFLUSH(); gcur = g; }                                  \
        acc[0] += w * __uint_as_float(v.x << 16);                               \
        acc[1] += w * __uint_as_float(v.x & 0xFFFF0000u);                       \
        acc[2] += w * __uint_as_float(v.y << 16);                               \
        acc[3] += w * __uint_as_float(v.y & 0xFFFF0000u);                       \
        acc[4] += w * __uint_as_float(v.z << 16);                               \
        acc[5] += w * __uint_as_float(v.z & 0xFFFF0000u);                       \
        acc[6] += w * __uint_as_float(v.w << 16);                               \
        acc[7] += w * __uint_as_float(v.w & 0xFFFF0000u);                       \
    }
    long long p = base + q;
    for (; p + 24 < end; p += 32) {
        unsigned m0 = meta[p];
        unsigned m1 = meta[p + 8];
        unsigned m2 = meta[p + 16];
        unsigned m3 = meta[p + 24];
        uint4 v0 = hs1q[(size_t)(m0 & 0x1FFFFu) * 8 + l8];
        uint4 v1 = hs1q[(size_t)(m1 & 0x1FFFFu) * 8 + l8];
        uint4 v2 = hs1q[(size_t)(m2 & 0x1FFFFu) * 8 + l8];
        uint4 v3 = hs1q[(size_t)(m3 & 0x1FFFFu) * 8 + l8];
        STEP(m0, v0) STEP(m1, v1) STEP(m2, v2) STEP(m3, v3)
    }
    for (; p < end; p += 8) {
        unsigned m = meta[p];
        uint4 v = hs1q[(size_t)(m & 0x1FFFFu) * 8 + l8];
        STEP(m, v)
    }
    // final flush
    {
        int g0 = __shfl(gcur, 0);
        if (g0 >= 0 && __all(gcur == g0)) {
#pragma unroll
            for (int k = 0; k < 8; ++k) {
                acc[k] += __shfl_xor(acc[k], 8);
                acc[k] += __shfl_xor(acc[k], 16);
                acc[k] += __shfl_xor(acc[k], 32);
            }
            if (q == 0) {
                float* dp = P + (size_t)(wid & (NSLICE - 1)) * (NGRAPH * 64)
                              + (size_t)g0 * 64 + (l8 << 3);
#pragma unroll
                for (int k = 0; k < 8; ++k) atomicAdd(dp + k, acc[k]);
            }
        } else {
            GFLUSH();
        }
    }
#undef STEP
#undef GFLUSH
}

// out[g][j] = (sum_slices P[g]/count_g) . W2[:,j] + b2[j]  (0 if empty graph)
__global__ void k_out(const float* __restrict__ P, const int* __restrict__ start,
                      const void* __restrict__ W2, const void* __restrict__ b2v,
                      const void* __restrict__ x, void* __restrict__ out) {
    __shared__ float pm[64];
    int isbf = probe_isbf(x);       // probe x (large), NOT W2
    int g = blockIdx.x, j = threadIdx.x;
    int c = start[g + 1] - start[g];
    if (j < 64) {
        float v = 0.f;
        for (int s = 0; s < NSLICE; ++s) v += P[(size_t)s * NGRAPH * 64 + g * 64 + j];
        pm[j] = (c > 0) ? v / (float)c : 0.0f;
    }
    __syncthreads();
    float acc = 0.0f;
    if (c > 0) {
        acc = fld(b2v, j, isbf);
        for (int k = 0; k < 64; ++k) acc += pm[k] * fld(W2, k * 128 + j, isbf);
    }
    if (isbf) ((bf16*)out)[g * 128 + j] = __float2bfloat16(acc);
    else      ((float*)out)[g * 128 + j] = acc;
}

extern "C" void kernel_launch(void* const* d_in, const int* in_sizes, int n_in,
                              void* d_out, int out_size, void* d_ws, size_t ws_size,
                              hipStream_t stream) {
    const void* x    = d_in[0];
    const void* ei   = d_in[1];   // edge_index [2,E] flat: src row then dst row
    const void* batch= d_in[2];
    const void* W1   = d_in[3];
    const void* b1   = d_in[4];
    const void* W2   = d_in[5];
    const void* b2   = d_in[6];

    const int N = in_sizes[0] / 3;
    const int E = in_sizes[1] / 2;
    const int Etot = E + N;
    const int NB = (N + 255) / 256;          // dst buckets (391)

    // ---- workspace layout (512B aligned), total ~31 MB ----
    char* ws = (char*)d_ws;
    size_t off = 0;
    auto alloc = [&](size_t bytes) {
        size_t o = off;
        off = (off + bytes + 511) & ~(size_t)511;
        return o;
    };
    int* gcur     = (int*)(ws + alloc((size_t)(NB + N) * 4));  // gcur[NB] ++ deg[N]
    int* deg      = gcur + NB;
    int* start    = (int*)(ws + alloc((size_t)(NGRAPH + 1) * 4));
    unsigned* edges2 = (unsigned*)(ws + alloc(((size_t)NB << CAPLG) * 4));
    unsigned* meta= (unsigned*)(ws + alloc((size_t)Etot * 4));
    float4* xs    = (float4*)(ws + alloc((size_t)N * 16));
    bf16* hs1     = (bf16*)(ws + alloc((size_t)N * 64 * 2));
    float* P      = (float*)(ws + alloc((size_t)NSLICE * NGRAPH * 64 * 4));
    (void)ws_size;

    (void)hipMemsetAsync(gcur, 0, (size_t)(NB + N) * 4, stream);

    const int sb = (E + TILE_S - 1) / TILE_S;       // 391

    // gather2: 2048 blocks -> 8192 waves (32/CU), edge-balanced chunks
    const int g2blocks = 2048;
    const int g2waves = g2blocks * 4;
    const int chunk = (Etot + g2waves - 1) / g2waves;

    k_split<<<sb, 256, 0, stream>>>(ei, edges2, gcur, deg, (float4*)P, E, NB);
    k_deg<<<NB, 256, 0, stream>>>(batch, x, ei, deg, xs, start, N);
    k_sortl1<<<NB, 256, 0, stream>>>(edges2, batch, x, ei, gcur, deg, xs,
                                     W1, b1, meta, hs1, N);
    k_gather2<<<g2blocks, 256, 0, stream>>>((const uint4*)hs1, meta, P, Etot, chunk);
    k_out<<<NGRAPH, 128, 0, stream>>>(P, start, W2, b2, x, d_out);
}

// Round 13
// 185.221 us; speedup vs baseline: 1.2551x; 1.2551x over previous
//
#include <hip/hip_runtime.h>
#include <hip/hip_bf16.h>

// 2-layer GCN + mean pool. N=100000, E=1600000, G=128. dims 3 -> 64 -> 128.
//   h1  = relu( (A_hat x) @ W1 + b1 )
//   out = (mean_g (A_hat h1)) @ W2 + b2
//
// R22 -> R23 (revert deg-atomics; bank best-known state):
//   R22's per-edge global atomicAdd(&deg[dst]) added ~53MB of coherence
//   RMW traffic (WRITE 7 -> 60MB), k_split 75.7us, total 232. Scattered
//   fine-grain global atomics ~32B each — never again on this chip.
//   This round = R20 composition + R21's k_bscan elimination:
//   * k_split: R20 body (P-zero, reg-cached single ei read, NO deg atomic).
//   * k_deg: R20 body (edges2 LDS histogram -> deg, xs, start).
//   * k_sortl1: R21 inline-mbase (block-reduce over gcur; proven neutral).
//   * k_gather2: FROZEN 4-deep/24-VGPR (queue-bound ~48us floor; 8-deep
//     and src-partition and MLP all proven non-wins).
//   6 dispatches: memset, split, deg, sortl1, gather2, out.

typedef __hip_bfloat16 bf16;
#define NGRAPH 128
#define NSLICE 8
#define TILE_S 4096
#define CAPLG  13      // per-bucket edges2 capacity = 8192
#define SCAP   8192    // k_sortl1 LDS stage capacity (mean 4096+256, 60 sigma)

__device__ __forceinline__ float b2f(bf16 v) { return __bfloat162float(v); }
__device__ __forceinline__ float fld(const void* p, long long i, int isbf) {
    return isbf ? b2f(((const bf16*)p)[i]) : ((const float*)p)[i];
}
__device__ __forceinline__ int ild(const void* p, long long i, int is64) {
    return is64 ? (int)((const long long*)p)[i] : ((const int*)p)[i];
}
// dtype probes: 2 cache lines each on LARGE buffers only (x: 600KB+, ei: 12MB+)
__device__ __forceinline__ int probe_is64(const void* ei) {
    int lane = threadIdx.x & 63;
    const int* w = (const int*)ei;
    unsigned long long bz = __ballot(w[2 * lane + 1] == 0);
    return (__popcll(bz) >= 56) ? 1 : 0;
}
__device__ __forceinline__ int probe_isbf(const void* x) {
    int lane = threadIdx.x & 63;
    const unsigned short* u = (const unsigned short*)x;
    int e0 = (u[2 * lane] >> 7) & 0xFF;
    int e1 = (u[2 * (lane + 64)] >> 7) & 0xFF;
    int good = __popcll(__ballot(e0 >= 90 && e0 <= 135))
             + __popcll(__ballot(e1 >= 90 && e1 <= 135));
    return (good >= 96) ? 1 : 0;
}

// ---- multisplit by dst bucket, self-counting, single ei read ------------
// edges2[b<<CAPLG ... ] = src | dloc<<24 for bucket b; gcur[b] ends = count.
__global__ void k_split(const void* __restrict__ ei, unsigned* __restrict__ edges2,
                        int* __restrict__ gcur, float4* __restrict__ P4,
                        int E, int NB) {
    // stripe-zero P (16384 float4s); safe: gather2 launches much later
    for (int k = blockIdx.x * 256 + threadIdx.x; k < NSLICE * NGRAPH * 16;
         k += gridDim.x * 256)
        P4[k] = make_float4(0.f, 0.f, 0.f, 0.f);
    __shared__ int hist[512], scan_[512], gbase[512], lcur[512];
    __shared__ int2 stage[TILE_S];
    int is64 = probe_is64(ei);
    long long base = (long long)blockIdx.x * TILE_S;
    int lim = (int)min((long long)TILE_S, (long long)E - base);
    for (int b = threadIdx.x; b < 512; b += 256) hist[b] = 0;
    __syncthreads();
    int dreg[16], sreg[16];
#pragma unroll
    for (int j = 0; j < 16; ++j) {
        int k = threadIdx.x + (j << 8);
        if (k < lim) {
            int d = ild(ei, (long long)E + base + k, is64);
            int s = ild(ei, base + k, is64);
            dreg[j] = d; sreg[j] = s;
            atomicAdd(&hist[d >> 8], 1);
        } else dreg[j] = -1;
    }
    __syncthreads();
    // parallel exclusive scan of hist (512 entries, 256 threads, Hillis-Steele)
    {
        int i0 = threadIdx.x, i1 = threadIdx.x + 256;
        scan_[i0] = hist[i0]; scan_[i1] = hist[i1];
        __syncthreads();
        for (int d = 1; d < 512; d <<= 1) {
            int t0 = (i0 >= d) ? scan_[i0 - d] : 0;
            int t1 = (i1 >= d) ? scan_[i1 - d] : 0;
            __syncthreads();
            scan_[i0] += t0; scan_[i1] += t1;
            __syncthreads();
        }
        int e0 = scan_[i0] - hist[i0];
        int e1 = scan_[i1] - hist[i1];
        __syncthreads();
        scan_[i0] = e0; scan_[i1] = e1;
        __syncthreads();
    }
    for (int b = threadIdx.x; b < NB; b += 256) {
        lcur[b] = scan_[b];
        gbase[b] = hist[b] ? atomicAdd(&gcur[b], hist[b]) : 0;
    }
    __syncthreads();
#pragma unroll
    for (int j = 0; j < 16; ++j) {
        if (dreg[j] >= 0) {
            int p = atomicAdd(&lcur[dreg[j] >> 8], 1);
            stage[p] = make_int2(dreg[j], sreg[j]);
        }
    }
    __syncthreads();
    for (int t = threadIdx.x; t < lim; t += 256) {
        int2 r = stage[t];
        int b = r.x >> 8;
        edges2[((size_t)b << CAPLG) + gbase[b] + (t - scan_[b])] =
            (unsigned)r.y | ((unsigned)(r.x & 255) << 24);
    }
}

// ---- per-bucket degree pass: deg, xs = dinv*x, start --------------------
__global__ void k_deg(const unsigned* __restrict__ edges2, const int* __restrict__ gcur,
                      const void* __restrict__ batch, const void* __restrict__ x,
                      const void* __restrict__ ei,
                      float4* __restrict__ xs, int* __restrict__ deg,
                      int* __restrict__ start, int N) {
    __shared__ int hist[256];
    int b = blockIdx.x;
    int node0 = b << 8;
    int nloc = min(256, N - node0);
    int is64 = probe_is64(ei);
    int isbf = probe_isbf(x);
    int i = threadIdx.x;
    if (i < nloc) hist[i] = 0;
    __syncthreads();
    size_t rbase = (size_t)b << CAPLG;
    int rcnt = gcur[b];
    for (int t = i; t < rcnt; t += 256)
        atomicAdd(&hist[edges2[rbase + t] >> 24], 1);
    __syncthreads();
    if (i < nloc) {
        int node = node0 + i;
        int dg = hist[i];
        deg[node] = dg;
        float di = rsqrtf((float)(dg + 1));
        xs[node] = make_float4(di * fld(x, 3LL * node, isbf),
                               di * fld(x, 3LL * node + 1, isbf),
                               di * fld(x, 3LL * node + 2, isbf), 0.0f);
        int g = ild(batch, node, is64);
        int gp = (node == 0) ? -1 : ild(batch, node - 1, is64);
        for (int q = gp + 1; q <= g; ++q) start[q] = node;
        if (node == N - 1)
            for (int q = g + 1; q <= NGRAPH; ++q) start[q] = N;
    }
}

// ---- fused: counting-sort meta build + layer-1 GEMM --------------------
// meta = src | g<<17 | min(deg,255)<<24; slot 0 of each row = self record.
// mbase computed inline: bktoff[b] = sum_{j<b} gcur[j] + node0 (nloc==256
// for all j<b). Aggregation reads LDS stage; hs1 written here.
__global__ void k_sortl1(const unsigned* __restrict__ edges2, const void* __restrict__ batch,
                         const void* __restrict__ x, const void* __restrict__ ei,
                         const int* __restrict__ gcur,
                         const int* __restrict__ deg, const float4* __restrict__ xs,
                         const void* __restrict__ W1, const void* __restrict__ b1,
                         unsigned* __restrict__ meta, bf16* __restrict__ hs1, int N) {
    __shared__ int loff[257], lcur[256], sc[256];
    __shared__ unsigned gdeg[256];
    __shared__ unsigned stage[SCAP];
    __shared__ float w[256];        // [0..191]=W1 (3x64 row-major), [192..255]=b1
    __shared__ float ag[256][4];
    int b = blockIdx.x;
    int node0 = b << 8;
    int nloc = min(256, N - node0);
    int is64 = probe_is64(ei);
    int isbf = probe_isbf(x);
    int i = threadIdx.x;
    if (i < 192) w[i] = fld(W1, i, isbf);
    if (i < 64) w[192 + i] = fld(b1, i, isbf);
    size_t rbase = (size_t)b << CAPLG;
    int rcnt = gcur[b];
    // inline mbase: block-reduce sum of gcur[0..b-1]
    int partial = 0;
    for (int j = i; j < b; j += 256) partial += gcur[j];
    sc[i] = partial;
    __syncthreads();
    for (int d = 128; d > 0; d >>= 1) {
        if (i < d) sc[i] += sc[i + d];
        __syncthreads();
    }
    int mbase = sc[0] + node0;
    __syncthreads();
    // register-cache first 4096 records (record 0xFFFFFFFF impossible: src<2^17)
    unsigned rc[16];
    int ncache = min(rcnt, 4096);
#pragma unroll
    for (int j = 0; j < 16; ++j) {
        int t = i + (j << 8);
        rc[j] = (t < ncache) ? edges2[rbase + t] : 0xFFFFFFFFu;
    }
    int dg = (i < nloc) ? deg[node0 + i] : 0;
    // exclusive scan of (deg+1)
    int v = (i < nloc) ? dg + 1 : 0;
    sc[i] = v;
    __syncthreads();
    for (int d = 1; d < 256; d <<= 1) {
        int t = (i >= d) ? sc[i - d] : 0;
        __syncthreads();
        sc[i] += t;
        __syncthreads();
    }
    if (i < nloc) loff[i] = sc[i] - v;
    if (i == nloc - 1) loff[nloc] = sc[i];
    __syncthreads();
    if (i < nloc) {
        int node = node0 + i;
        int g = ild(batch, node, is64);
        unsigned gd = ((unsigned)g << 17) | ((unsigned)min(dg, 255) << 24);
        gdeg[i] = gd;
        lcur[i] = loff[i] + 1;                 // slot 0 = self record
        stage[loff[i]] = (unsigned)node | gd;
    }
    __syncthreads();
#pragma unroll
    for (int j = 0; j < 16; ++j) {
        if (rc[j] != 0xFFFFFFFFu) {
            int dl = (int)(rc[j] >> 24);
            int p = atomicAdd(&lcur[dl], 1);
            if (p < SCAP) stage[p] = (rc[j] & 0x1FFFFu) | gdeg[dl];
        }
    }
    for (int t = 4096 + i; t < rcnt; t += 256) {
        unsigned r = edges2[rbase + t];
        int dl = (int)(r >> 24);
        int p = atomicAdd(&lcur[dl], 1);
        if (p < SCAP) stage[p] = (r & 0x1FFFFu) | gdeg[dl];
    }
    __syncthreads();
    int total = loff[nloc];
    int totc = min(total, SCAP);
    for (int t = i; t < totc; t += 256) meta[mbase + t] = stage[t];
    // layer-1 aggregation from LDS stage + tiny GEMM
    if (i < nloc) {
        float ax = 0.f, ay = 0.f, az = 0.f;
        int p1 = min(loff[i + 1], SCAP);
        for (int p = loff[i]; p < p1; ++p) {
            float4 vv = xs[stage[p] & 0x1FFFFu];
            ax += vv.x; ay += vv.y; az += vv.z;
        }
        float di = rsqrtf((float)(dg + 1));
        ag[i][0] = di * ax; ag[i][1] = di * ay; ag[i][2] = di * az;
        ag[i][3] = di;
    }
    __syncthreads();
    for (int t = i; t < (nloc << 6); t += 256) {
        int ii = t >> 6, j = t & 63;
        float acc = ag[ii][0] * w[j] + ag[ii][1] * w[64 + j] + ag[ii][2] * w[128 + j]
                  + w[192 + j];
        hs1[(size_t)(node0 + ii) * 64 + j] = __float2bfloat16(ag[ii][3] * fmaxf(acc, 0.0f));
    }
}

// ---- layer 2 + pool: edge-balanced meta stream (register acc) -----------
// Wave = 8 groups x 8 lanes. Group q walks edges base+q, base+q+8, ... (a
// stride-8 subsequence of the dst-sorted stream -> g stays monotone). Each
// lane loads 16B (uint4 = 8 bf16) of the 128B hs1 row: one dwordx4
// instruction fetches 8 edges' rows (1KB). 4-deep unroll (R20-proven best:
// 8-deep regressed via occupancy). Register acc; R13 flush discipline.
__global__ void k_gather2(const uint4* __restrict__ hs1q, const unsigned* __restrict__ meta,
                          float* __restrict__ P, int Etot, int chunk) {
    int wid = (blockIdx.x * blockDim.x + threadIdx.x) >> 6;
    int lane = threadIdx.x & 63;
    int q = lane >> 3;          // group 0..7
    int l8 = lane & 7;          // lane in group -> features [8*l8, 8*l8+8)
    long long base = (long long)wid * chunk;
    if (base >= Etot) return;
    long long end = base + chunk;
    if (end > Etot) end = Etot;
    float acc[8] = {0.f, 0.f, 0.f, 0.f, 0.f, 0.f, 0.f, 0.f};
    int gcur = -1;
#define GFLUSH()                                                                \
    if (gcur >= 0) {                                                            \
        float* dp = P + (size_t)q * (NGRAPH * 64) + (size_t)gcur * 64 + (l8 << 3); \
        _Pragma("unroll")                                                       \
        for (int k = 0; k < 8; ++k) { atomicAdd(dp + k, acc[k]); acc[k] = 0.f; }\
    }
#define STEP(m, v)                                                              \
    {                                                                           \
        int g = (int)((m >> 17) & 0x7Fu);                                       \
        float w = rsqrtf((float)((m >> 24) & 0xFFu) + 1.0f);                    \
        if (g != gcur) { GFLUSH(); gcur = g; }                                  \
        acc[0] += w * __uint_as_float(v.x << 16);                               \
        acc[1] += w * __uint_as_float(v.x & 0xFFFF0000u);                       \
        acc[2] += w * __uint_as_float(v.y << 16);                               \
        acc[3] += w * __uint_as_float(v.y & 0xFFFF0000u);                       \
        acc[4] += w * __uint_as_float(v.z << 16);                               \
        acc[5] += w * __uint_as_float(v.z & 0xFFFF0000u);                       \
        acc[6] += w * __uint_as_float(v.w << 16);                               \
        acc[7] += w * __uint_as_float(v.w & 0xFFFF0000u);                       \
    }
    long long p = base + q;
    for (; p + 24 < end; p += 32) {
        unsigned m0 = meta[p];
        unsigned m1 = meta[p + 8];
        unsigned m2 = meta[p + 16];
        unsigned m3 = meta[p + 24];
        uint4 v0 = hs1q[(size_t)(m0 & 0x1FFFFu) * 8 + l8];
        uint4 v1 = hs1q[(size_t)(m1 & 0x1FFFFu) * 8 + l8];
        uint4 v2 = hs1q[(size_t)(m2 & 0x1FFFFu) * 8 + l8];
        uint4 v3 = hs1q[(size_t)(m3 & 0x1FFFFu) * 8 + l8];
        STEP(m0, v0) STEP(m1, v1) STEP(m2, v2) STEP(m3, v3)
    }
    for (; p < end; p += 8) {
        unsigned m = meta[p];
        uint4 v = hs1q[(size_t)(m & 0x1FFFFu) * 8 + l8];
        STEP(m, v)
    }
    // final flush
    {
        int g0 = __shfl(gcur, 0);
        if (g0 >= 0 && __all(gcur == g0)) {
#pragma unroll
            for (int k = 0; k < 8; ++k) {
                acc[k] += __shfl_xor(acc[k], 8);
                acc[k] += __shfl_xor(acc[k], 16);
                acc[k] += __shfl_xor(acc[k], 32);
            }
            if (q == 0) {
                float* dp = P + (size_t)(wid & (NSLICE - 1)) * (NGRAPH * 64)
                              + (size_t)g0 * 64 + (l8 << 3);
#pragma unroll
                for (int k = 0; k < 8; ++k) atomicAdd(dp + k, acc[k]);
            }
        } else {
            GFLUSH();
        }
    }
#undef STEP
#undef GFLUSH
}

// out[g][j] = (sum_slices P[g]/count_g) . W2[:,j] + b2[j]  (0 if empty graph)
__global__ void k_out(const float* __restrict__ P, const int* __restrict__ start,
                      const void* __restrict__ W2, const void* __restrict__ b2v,
                      const void* __restrict__ x, void* __restrict__ out) {
    __shared__ float pm[64];
    int isbf = probe_isbf(x);       // probe x (large), NOT W2
    int g = blockIdx.x, j = threadIdx.x;
    int c = start[g + 1] - start[g];
    if (j < 64) {
        float v = 0.f;
        for (int s = 0; s < NSLICE; ++s) v += P[(size_t)s * NGRAPH * 64 + g * 64 + j];
        pm[j] = (c > 0) ? v / (float)c : 0.0f;
    }
    __syncthreads();
    float acc = 0.0f;
    if (c > 0) {
        acc = fld(b2v, j, isbf);
        for (int k = 0; k < 64; ++k) acc += pm[k] * fld(W2, k * 128 + j, isbf);
    }
    if (isbf) ((bf16*)out)[g * 128 + j] = __float2bfloat16(acc);
    else      ((float*)out)[g * 128 + j] = acc;
}

extern "C" void kernel_launch(void* const* d_in, const int* in_sizes, int n_in,
                              void* d_out, int out_size, void* d_ws, size_t ws_size,
                              hipStream_t stream) {
    const void* x    = d_in[0];
    const void* ei   = d_in[1];   // edge_index [2,E] flat: src row then dst row
    const void* batch= d_in[2];
    const void* W1   = d_in[3];
    const void* b1   = d_in[4];
    const void* W2   = d_in[5];
    const void* b2   = d_in[6];

    const int N = in_sizes[0] / 3;
    const int E = in_sizes[1] / 2;
    const int Etot = E + N;
    const int NB = (N + 255) / 256;          // dst buckets (391)

    // ---- workspace layout (512B aligned), total ~31 MB ----
    char* ws = (char*)d_ws;
    size_t off = 0;
    auto alloc = [&](size_t bytes) {
        size_t o = off;
        off = (off + bytes + 511) & ~(size_t)511;
        return o;
    };
    int* gcur     = (int*)(ws + alloc((size_t)NB * 4));
    int* start    = (int*)(ws + alloc((size_t)(NGRAPH + 1) * 4));
    int* deg      = (int*)(ws + alloc((size_t)N * 4));
    unsigned* edges2 = (unsigned*)(ws + alloc(((size_t)NB << CAPLG) * 4));
    unsigned* meta= (unsigned*)(ws + alloc((size_t)Etot * 4));
    float4* xs    = (float4*)(ws + alloc((size_t)N * 16));
    bf16* hs1     = (bf16*)(ws + alloc((size_t)N * 64 * 2));
    float* P      = (float*)(ws + alloc((size_t)NSLICE * NGRAPH * 64 * 4));
    (void)ws_size;

    (void)hipMemsetAsync(gcur, 0, (size_t)NB * 4, stream);

    const int sb = (E + TILE_S - 1) / TILE_S;       // 391

    // gather2: 2048 blocks -> 8192 waves (32/CU), edge-balanced chunks
    const int g2blocks = 2048;
    const int g2waves = g2blocks * 4;
    const int chunk = (Etot + g2waves - 1) / g2waves;

    k_split<<<sb, 256, 0, stream>>>(ei, edges2, gcur, (float4*)P, E, NB);
    k_deg<<<NB, 256, 0, stream>>>(edges2, gcur, batch, x, ei, xs, deg, start, N);
    k_sortl1<<<NB, 256, 0, stream>>>(edges2, batch, x, ei, gcur, deg, xs,
                                     W1, b1, meta, hs1, N);
    k_gather2<<<g2blocks, 256, 0, stream>>>((const uint4*)hs1, meta, P, Etot, chunk);
    k_out<<<NGRAPH, 128, 0, stream>>>(P, start, W2, b2, x, d_out);
}

// Round 14
// 174.457 us; speedup vs baseline: 1.3325x; 1.0617x over previous
//
#include <hip/hip_runtime.h>
#include <hip/hip_bf16.h>

// 2-layer GCN + mean pool. N=100000, E=1600000, G=128. dims 3 -> 64 -> 128.
//   h1  = relu( (A_hat x) @ W1 + b1 )
//   out = (mean_g (A_hat h1)) @ W2 + b2
//
// R23 -> R24 (preprocessing occupancy + sync diet; 185 -> predict ~167):
//   Non-gather2 is 134us vs ~8us HBM floor: overhead-bound. The 391-block
//   bucket kernels run at 19% wave occupancy with 18-sync scans. Fix:
//   * k_split/k_deg/k_sortl1 move to 512-thread blocks (391x8=3128 waves,
//     per-block serial work halves; 8 reg edges/thread).
//   * Hillis-Steele scans -> wave __shfl_up scans + 1 LDS segment combine
//     (k_split 18 syncs -> 2; k_sortl1 scan 16 -> 2, mbase reduce 8 -> 1).
//   * segment sums reuse gbase/sc scratch: k_split LDS stays 40960B
//     (4 blocks/CU preserved). No new atomics (R22 lesson).
//   k_gather2 FROZEN (4-deep/24VGPR, ~48-51us queue-bound floor). k_out
//   unchanged. 6 dispatches.

typedef __hip_bfloat16 bf16;
#define NGRAPH 128
#define NSLICE 8
#define TILE_S 4096
#define CAPLG  13      // per-bucket edges2 capacity = 8192
#define SCAP   8192    // k_sortl1 LDS stage capacity (mean 4096+256, 60 sigma)

__device__ __forceinline__ float b2f(bf16 v) { return __bfloat162float(v); }
__device__ __forceinline__ float fld(const void* p, long long i, int isbf) {
    return isbf ? b2f(((const bf16*)p)[i]) : ((const float*)p)[i];
}
__device__ __forceinline__ int ild(const void* p, long long i, int is64) {
    return is64 ? (int)((const long long*)p)[i] : ((const int*)p)[i];
}
// dtype probes: 2 cache lines each on LARGE buffers only (x: 600KB+, ei: 12MB+)
__device__ __forceinline__ int probe_is64(const void* ei) {
    int lane = threadIdx.x & 63;
    const int* w = (const int*)ei;
    unsigned long long bz = __ballot(w[2 * lane + 1] == 0);
    return (__popcll(bz) >= 56) ? 1 : 0;
}
__device__ __forceinline__ int probe_isbf(const void* x) {
    int lane = threadIdx.x & 63;
    const unsigned short* u = (const unsigned short*)x;
    int e0 = (u[2 * lane] >> 7) & 0xFF;
    int e1 = (u[2 * (lane + 64)] >> 7) & 0xFF;
    int good = __popcll(__ballot(e0 >= 90 && e0 <= 135))
             + __popcll(__ballot(e1 >= 90 && e1 <= 135));
    return (good >= 96) ? 1 : 0;
}
// inclusive wave scan via shfl_up (64 lanes)
__device__ __forceinline__ int wave_iscan(int v, int lane) {
#pragma unroll
    for (int d = 1; d < 64; d <<= 1) {
        int t = __shfl_up(v, d);
        if (lane >= d) v += t;
    }
    return v;
}

// ---- multisplit by dst bucket, self-counting, single ei read ------------
// 512 threads. edges2[b<<CAPLG ...] = src | dloc<<24; gcur[b] ends = count.
__global__ void k_split(const void* __restrict__ ei, unsigned* __restrict__ edges2,
                        int* __restrict__ gcur, float4* __restrict__ P4,
                        int E, int NB) {
    // stripe-zero P (16384 float4s); safe: gather2 launches much later
    for (int k = blockIdx.x * 512 + threadIdx.x; k < NSLICE * NGRAPH * 16;
         k += gridDim.x * 512)
        P4[k] = make_float4(0.f, 0.f, 0.f, 0.f);
    __shared__ int hist[512], scan_[512], gbase[512], lcur[512];
    __shared__ int2 stage[TILE_S];
    int i = threadIdx.x;
    int lane = i & 63, wv = i >> 6;
    int is64 = probe_is64(ei);
    long long base = (long long)blockIdx.x * TILE_S;
    int lim = (int)min((long long)TILE_S, (long long)E - base);
    hist[i] = 0;
    __syncthreads();
    int dreg[8], sreg[8];
#pragma unroll
    for (int j = 0; j < 8; ++j) {
        int k = i + (j << 9);
        if (k < lim) {
            int d = ild(ei, (long long)E + base + k, is64);
            int s = ild(ei, base + k, is64);
            dreg[j] = d; sreg[j] = s;
            atomicAdd(&hist[d >> 8], 1);
        } else dreg[j] = -1;
    }
    __syncthreads();
    // exclusive scan of hist[512]: per-wave shfl scan + segment combine.
    // gbase[0..7] temporarily holds segment sums (overwritten later).
    int v = hist[i];
    int isc = wave_iscan(v, lane);
    if (lane == 63) gbase[wv] = isc;
    __syncthreads();
    int sbase = 0;
    for (int s = 0; s < wv; ++s) sbase += gbase[s];
    scan_[i] = sbase + isc - v;           // exclusive
    __syncthreads();
    if (i < NB) {
        lcur[i] = scan_[i];
        gbase[i] = hist[i] ? atomicAdd(&gcur[i], hist[i]) : 0;
    }
    __syncthreads();
#pragma unroll
    for (int j = 0; j < 8; ++j) {
        if (dreg[j] >= 0) {
            int p = atomicAdd(&lcur[dreg[j] >> 8], 1);
            stage[p] = make_int2(dreg[j], sreg[j]);
        }
    }
    __syncthreads();
    for (int t = i; t < lim; t += 512) {
        int2 r = stage[t];
        int b = r.x >> 8;
        edges2[((size_t)b << CAPLG) + gbase[b] + (t - scan_[b])] =
            (unsigned)r.y | ((unsigned)(r.x & 255) << 24);
    }
}

// ---- per-bucket degree pass (512 thr): deg, xs = dinv*x, start ----------
__global__ void k_deg(const unsigned* __restrict__ edges2, const int* __restrict__ gcur,
                      const void* __restrict__ batch, const void* __restrict__ x,
                      const void* __restrict__ ei,
                      float4* __restrict__ xs, int* __restrict__ deg,
                      int* __restrict__ start, int N) {
    __shared__ int hist[256];
    int b = blockIdx.x;
    int node0 = b << 8;
    int nloc = min(256, N - node0);
    int is64 = probe_is64(ei);
    int isbf = probe_isbf(x);
    int i = threadIdx.x;
    if (i < 256) hist[i] = 0;
    __syncthreads();
    size_t rbase = (size_t)b << CAPLG;
    int rcnt = gcur[b];
    for (int t = i; t < rcnt; t += 512)
        atomicAdd(&hist[edges2[rbase + t] >> 24], 1);
    __syncthreads();
    if (i < nloc) {
        int node = node0 + i;
        int dg = hist[i];
        deg[node] = dg;
        float di = rsqrtf((float)(dg + 1));
        xs[node] = make_float4(di * fld(x, 3LL * node, isbf),
                               di * fld(x, 3LL * node + 1, isbf),
                               di * fld(x, 3LL * node + 2, isbf), 0.0f);
        int g = ild(batch, node, is64);
        int gp = (node == 0) ? -1 : ild(batch, node - 1, is64);
        for (int q = gp + 1; q <= g; ++q) start[q] = node;
        if (node == N - 1)
            for (int q = g + 1; q <= NGRAPH; ++q) start[q] = N;
    }
}

// ---- fused (512 thr): counting-sort meta build + layer-1 GEMM -----------
// meta = src | g<<17 | min(deg,255)<<24; slot 0 of each row = self record.
// mbase inline: sum_{j<b} gcur[j] + node0 (wave reduce + combine).
__global__ void k_sortl1(const unsigned* __restrict__ edges2, const void* __restrict__ batch,
                         const void* __restrict__ x, const void* __restrict__ ei,
                         const int* __restrict__ gcur,
                         const int* __restrict__ deg, const float4* __restrict__ xs,
                         const void* __restrict__ W1, const void* __restrict__ b1,
                         unsigned* __restrict__ meta, bf16* __restrict__ hs1, int N) {
    __shared__ int loff[257], lcur[256], sc[256];
    __shared__ unsigned gdeg[256];
    __shared__ unsigned stage[SCAP];
    __shared__ float w[256];        // [0..191]=W1 (3x64 row-major), [192..255]=b1
    __shared__ float ag[256][4];
    int b = blockIdx.x;
    int node0 = b << 8;
    int nloc = min(256, N - node0);
    int is64 = probe_is64(ei);
    int isbf = probe_isbf(x);
    int i = threadIdx.x;
    int lane = i & 63, wv = i >> 6;
    if (i < 192) w[i] = fld(W1, i, isbf);
    if (i >= 192 && i < 256) w[i] = fld(b1, i - 192, isbf);
    size_t rbase = (size_t)b << CAPLG;
    int rcnt = gcur[b];
    // inline mbase: wave-reduce partial sums of gcur[0..b-1], combine in sc[0..7]
    int partial = 0;
    for (int j = i; j < b; j += 512) partial += gcur[j];
#pragma unroll
    for (int d = 1; d < 64; d <<= 1) partial += __shfl_xor(partial, d);
    if (lane == 0) sc[wv] = partial;
    __syncthreads();
    int mbase = sc[0] + sc[1] + sc[2] + sc[3] + sc[4] + sc[5] + sc[6] + sc[7] + node0;
    __syncthreads();
    // register-cache first 4096 records (record 0xFFFFFFFF impossible: src<2^17)
    unsigned rc[8];
    int ncache = min(rcnt, 4096);
#pragma unroll
    for (int j = 0; j < 8; ++j) {
        int t = i + (j << 9);
        rc[j] = (t < ncache) ? edges2[rbase + t] : 0xFFFFFFFFu;
    }
    int dg = (i < nloc) ? deg[node0 + i] : 0;
    // exclusive scan of (deg+1) over 256 entries: waves 0-3 shfl scan
    int v = (i < nloc) ? dg + 1 : 0;
    int isc = 0;
    if (i < 256) isc = wave_iscan(v, lane);
    if (i < 256 && lane == 63) sc[wv] = isc;
    __syncthreads();
    if (i < 256) {
        int sbase = 0;
        for (int s = 0; s < wv; ++s) sbase += sc[s];
        if (i < nloc) loff[i] = sbase + isc - v;
        if (i == nloc - 1) loff[nloc] = sbase + isc;
    }
    __syncthreads();
    if (i < nloc) {
        int node = node0 + i;
        int g = ild(batch, node, is64);
        unsigned gd = ((unsigned)g << 17) | ((unsigned)min(dg, 255) << 24);
        gdeg[i] = gd;
        lcur[i] = loff[i] + 1;                 // slot 0 = self record
        stage[loff[i]] = (unsigned)node | gd;
    }
    __syncthreads();
#pragma unroll
    for (int j = 0; j < 8; ++j) {
        if (rc[j] != 0xFFFFFFFFu) {
            int dl = (int)(rc[j] >> 24);
            int p = atomicAdd(&lcur[dl], 1);
            if (p < SCAP) stage[p] = (rc[j] & 0x1FFFFu) | gdeg[dl];
        }
    }
    for (int t = 4096 + i; t < rcnt; t += 512) {
        unsigned r = edges2[rbase + t];
        int dl = (int)(r >> 24);
        int p = atomicAdd(&lcur[dl], 1);
        if (p < SCAP) stage[p] = (r & 0x1FFFFu) | gdeg[dl];
    }
    __syncthreads();
    int total = loff[nloc];
    int totc = min(total, SCAP);
    for (int t = i; t < totc; t += 512) meta[mbase + t] = stage[t];
    // layer-1 aggregation from LDS stage + tiny GEMM
    if (i < nloc) {
        float ax = 0.f, ay = 0.f, az = 0.f;
        int p1 = min(loff[i + 1], SCAP);
        for (int p = loff[i]; p < p1; ++p) {
            float4 vv = xs[stage[p] & 0x1FFFFu];
            ax += vv.x; ay += vv.y; az += vv.z;
        }
        float di = rsqrtf((float)(dg + 1));
        ag[i][0] = di * ax; ag[i][1] = di * ay; ag[i][2] = di * az;
        ag[i][3] = di;
    }
    __syncthreads();
    for (int t = i; t < (nloc << 6); t += 512) {
        int ii = t >> 6, j = t & 63;
        float acc = ag[ii][0] * w[j] + ag[ii][1] * w[64 + j] + ag[ii][2] * w[128 + j]
                  + w[192 + j];
        hs1[(size_t)(node0 + ii) * 64 + j] = __float2bfloat16(ag[ii][3] * fmaxf(acc, 0.0f));
    }
}

// ---- layer 2 + pool: edge-balanced meta stream (register acc) -----------
// FROZEN (R20 best): wave = 8 groups x 8 lanes, uint4 1KB loads, 4-deep
// unroll, register acc, R13 flush discipline.
__global__ void k_gather2(const uint4* __restrict__ hs1q, const unsigned* __restrict__ meta,
                          float* __restrict__ P, int Etot, int chunk) {
    int wid = (blockIdx.x * blockDim.x + threadIdx.x) >> 6;
    int lane = threadIdx.x & 63;
    int q = lane >> 3;          // group 0..7
    int l8 = lane & 7;          // lane in group -> features [8*l8, 8*l8+8)
    long long base = (long long)wid * chunk;
    if (base >= Etot) return;
    long long end = base + chunk;
    if (end > Etot) end = Etot;
    float acc[8] = {0.f, 0.f, 0.f, 0.f, 0.f, 0.f, 0.f, 0.f};
    int gcur = -1;
#define GFLUSH()                                                                \
    if (gcur >= 0) {                                                            \
        float* dp = P + (size_t)q * (NGRAPH * 64) + (size_t)gcur * 64 + (l8 << 3); \
        _Pragma("unroll")                                                       \
        for (int k = 0; k < 8; ++k) { atomicAdd(dp + k, acc[k]); acc[k] = 0.f; }\
    }
#define STEP(m, v)                                                              \
    {                                                                           \
        int g = (int)((m >> 17) & 0x7Fu);                                       \
        float w = rsqrtf((float)((m >> 24) & 0xFFu) + 1.0f);                    \
        if (g != gcur) { GFLUSH(); gcur = g; }                                  \
        acc[0] += w * __uint_as_float(v.x << 16);                               \
        acc[1] += w * __uint_as_float(v.x & 0xFFFF0000u);                       \
        acc[2] += w * __uint_as_float(v.y << 16);                               \
        acc[3] += w * __uint_as_float(v.y & 0xFFFF0000u);                       \
        acc[4] += w * __uint_as_float(v.z << 16);                               \
        acc[5] += w * __uint_as_float(v.z & 0xFFFF0000u);                       \
        acc[6] += w * __uint_as_float(v.w << 16);                               \
        acc[7] += w * __uint_as_float(v.w & 0xFFFF0000u);                       \
    }
    long long p = base + q;
    for (; p + 24 < end; p += 32) {
        unsigned m0 = meta[p];
        unsigned m1 = meta[p + 8];
        unsigned m2 = meta[p + 16];
        unsigned m3 = meta[p + 24];
        uint4 v0 = hs1q[(size_t)(m0 & 0x1FFFFu) * 8 + l8];
        uint4 v1 = hs1q[(size_t)(m1 & 0x1FFFFu) * 8 + l8];
        uint4 v2 = hs1q[(size_t)(m2 & 0x1FFFFu) * 8 + l8];
        uint4 v3 = hs1q[(size_t)(m3 & 0x1FFFFu) * 8 + l8];
        STEP(m0, v0) STEP(m1, v1) STEP(m2, v2) STEP(m3, v3)
    }
    for (; p < end; p += 8) {
        unsigned m = meta[p];
        uint4 v = hs1q[(size_t)(m & 0x1FFFFu) * 8 + l8];
        STEP(m, v)
    }
    // final flush
    {
        int g0 = __shfl(gcur, 0);
        if (g0 >= 0 && __all(gcur == g0)) {
#pragma unroll
            for (int k = 0; k < 8; ++k) {
                acc[k] += __shfl_xor(acc[k], 8);
                acc[k] += __shfl_xor(acc[k], 16);
                acc[k] += __shfl_xor(acc[k], 32);
            }
            if (q == 0) {
                float* dp = P + (size_t)(wid & (NSLICE - 1)) * (NGRAPH * 64)
                              + (size_t)g0 * 64 + (l8 << 3);
#pragma unroll
                for (int k = 0; k < 8; ++k) atomicAdd(dp + k, acc[k]);
            }
        } else {
            GFLUSH();
        }
    }
#undef STEP
#undef GFLUSH
}

// out[g][j] = (sum_slices P[g]/count_g) . W2[:,j] + b2[j]  (0 if empty graph)
__global__ void k_out(const float* __restrict__ P, const int* __restrict__ start,
                      const void* __restrict__ W2, const void* __restrict__ b2v,
                      const void* __restrict__ x, void* __restrict__ out) {
    __shared__ float pm[64];
    int isbf = probe_isbf(x);       // probe x (large), NOT W2
    int g = blockIdx.x, j = threadIdx.x;
    int c = start[g + 1] - start[g];
    if (j < 64) {
        float v = 0.f;
        for (int s = 0; s < NSLICE; ++s) v += P[(size_t)s * NGRAPH * 64 + g * 64 + j];
        pm[j] = (c > 0) ? v / (float)c : 0.0f;
    }
    __syncthreads();
    float acc = 0.0f;
    if (c > 0) {
        acc = fld(b2v, j, isbf);
        for (int k = 0; k < 64; ++k) acc += pm[k] * fld(W2, k * 128 + j, isbf);
    }
    if (isbf) ((bf16*)out)[g * 128 + j] = __float2bfloat16(acc);
    else      ((float*)out)[g * 128 + j] = acc;
}

extern "C" void kernel_launch(void* const* d_in, const int* in_sizes, int n_in,
                              void* d_out, int out_size, void* d_ws, size_t ws_size,
                              hipStream_t stream) {
    const void* x    = d_in[0];
    const void* ei   = d_in[1];   // edge_index [2,E] flat: src row then dst row
    const void* batch= d_in[2];
    const void* W1   = d_in[3];
    const void* b1   = d_in[4];
    const void* W2   = d_in[5];
    const void* b2   = d_in[6];

    const int N = in_sizes[0] / 3;
    const int E = in_sizes[1] / 2;
    const int Etot = E + N;
    const int NB = (N + 255) / 256;          // dst buckets (391)

    // ---- workspace layout (512B aligned), total ~31 MB ----
    char* ws = (char*)d_ws;
    size_t off = 0;
    auto alloc = [&](size_t bytes) {
        size_t o = off;
        off = (off + bytes + 511) & ~(size_t)511;
        return o;
    };
    int* gcur     = (int*)(ws + alloc((size_t)NB * 4));
    int* start    = (int*)(ws + alloc((size_t)(NGRAPH + 1) * 4));
    int* deg      = (int*)(ws + alloc((size_t)N * 4));
    unsigned* edges2 = (unsigned*)(ws + alloc(((size_t)NB << CAPLG) * 4));
    unsigned* meta= (unsigned*)(ws + alloc((size_t)Etot * 4));
    float4* xs    = (float4*)(ws + alloc((size_t)N * 16));
    bf16* hs1     = (bf16*)(ws + alloc((size_t)N * 64 * 2));
    float* P      = (float*)(ws + alloc((size_t)NSLICE * NGRAPH * 64 * 4));
    (void)ws_size;

    (void)hipMemsetAsync(gcur, 0, (size_t)NB * 4, stream);

    const int sb = (E + TILE_S - 1) / TILE_S;       // 391

    // gather2: 2048 blocks -> 8192 waves (32/CU), edge-balanced chunks
    const int g2blocks = 2048;
    const int g2waves = g2blocks * 4;
    const int chunk = (Etot + g2waves - 1) / g2waves;

    k_split<<<sb, 512, 0, stream>>>(ei, edges2, gcur, (float4*)P, E, NB);
    k_deg<<<NB, 512, 0, stream>>>(edges2, gcur, batch, x, ei, xs, deg, start, N);
    k_sortl1<<<NB, 512, 0, stream>>>(edges2, batch, x, ei, gcur, deg, xs,
                                     W1, b1, meta, hs1, N);
    k_gather2<<<g2blocks, 256, 0, stream>>>((const uint4*)hs1, meta, P, Etot, chunk);
    k_out<<<NGRAPH, 128, 0, stream>>>(P, start, W2, b2, x, d_out);
}